// Round 1
// baseline (1892.675 us; speedup 1.0000x reference)
//
#include <hip/hip_runtime.h>
#include <hip/hip_bf16.h>
#include <math.h>

// Problem constants (match reference)
static constexpr int kNTx   = 100000;
static constexpr int kNAddr = 150000;
static constexpr int kE     = 1500000;
static constexpr int kFTx   = 165;
static constexpr int kFAddr = 64;
static constexpr int kHid   = 32;   // per-head channels
static constexpr int kHO    = 64;   // concat output dim (2 heads x 32)

// ---------------------------------------------------------------------------
// Dense input projection: out[N,32] = X[N,K] @ W[K,32] + b
// block=256 -> 8 rows x 32 cols; W staged in LDS; X row broadcast across lanes.
// ---------------------------------------------------------------------------
template<int K>
__global__ void proj_kernel(const float* __restrict__ X, const float* __restrict__ W,
                            const float* __restrict__ bias, float* __restrict__ out, int N) {
  __shared__ float Wl[K * kHid];
  for (int i = threadIdx.x; i < K * kHid; i += blockDim.x) Wl[i] = W[i];
  __syncthreads();
  int row = blockIdx.x * (blockDim.x / kHid) + threadIdx.x / kHid;
  int col = threadIdx.x % kHid;
  if (row >= N) return;
  const float* xr = X + (size_t)row * K;
  float acc = 0.f;
  #pragma unroll 5
  for (int k = 0; k < K; ++k) acc = fmaf(xr[k], Wl[k * kHid + col], acc);
  out[(size_t)row * kHid + col] = acc + bias[col];
}

// ---------------------------------------------------------------------------
// hs = X @ W  ([N,64]) and al_s[n,h] = sum_c hs[n,h*32+c]*a_s[h,c]
// block=256 -> 4 rows x 64 cols (one wave per row). Half-wave = head.
// ---------------------------------------------------------------------------
template<int K>
__global__ void hs_als_kernel(const float* __restrict__ X, const float* __restrict__ W,
                              const float* __restrict__ a_s,
                              float* __restrict__ HS, float* __restrict__ ALS, int N) {
  __shared__ float Wl[K * kHO];
  __shared__ float asl[kHO];
  for (int i = threadIdx.x; i < K * kHO; i += blockDim.x) Wl[i] = W[i];
  if (threadIdx.x < kHO) asl[threadIdx.x] = a_s[threadIdx.x];
  __syncthreads();
  int row = blockIdx.x * (blockDim.x >> 6) + (threadIdx.x >> 6);
  int col = threadIdx.x & 63;
  if (row >= N) return;
  const float* xr = X + (size_t)row * K;
  float acc = 0.f;
  #pragma unroll 8
  for (int k = 0; k < K; ++k) acc = fmaf(xr[k], Wl[k * kHO + col], acc);
  HS[(size_t)row * kHO + col] = acc;
  // reduce acc * a_s over the 32 channels of this head (lanes within half-wave)
  float p = acc * asl[col];
  for (int off = 16; off >= 1; off >>= 1) p += __shfl_xor(p, off);
  if ((col & 31) == 0) ALS[(size_t)row * 2 + (col >> 5)] = p;
}

// ---------------------------------------------------------------------------
// al_d[n,h] = X[n,:] @ Vd[:,h] where Vd[k,h] = sum_c W[k,h*32+c] * a_d[h,c]
// (never materializes hd). block=256 -> 128 rows x 2 heads.
// ---------------------------------------------------------------------------
template<int K>
__global__ void ald_kernel(const float* __restrict__ X, const float* __restrict__ W,
                           const float* __restrict__ a_d, float* __restrict__ ALD, int N) {
  __shared__ float Vd[K * 2];
  __shared__ float adl[kHO];
  if (threadIdx.x < kHO) adl[threadIdx.x] = a_d[threadIdx.x];
  __syncthreads();
  for (int i = threadIdx.x; i < K * 2; i += blockDim.x) {
    int k = i >> 1, h = i & 1;
    float s = 0.f;
    #pragma unroll
    for (int c = 0; c < kHid; ++c) s = fmaf(W[k * kHO + h * kHid + c], adl[h * kHid + c], s);
    Vd[i] = s;
  }
  __syncthreads();
  int row = blockIdx.x * (blockDim.x >> 1) + (threadIdx.x >> 1);
  int h = threadIdx.x & 1;
  if (row >= N) return;
  const float* xr = X + (size_t)row * K;
  float acc = 0.f;
  #pragma unroll 8
  for (int k = 0; k < K; ++k) acc = fmaf(xr[k], Vd[k * 2 + h], acc);
  ALD[(size_t)row * 2 + h] = acc;
}

// ---------------------------------------------------------------------------
// CSR build: count -> exclusive scan -> scatter
// ---------------------------------------------------------------------------
__global__ void count_kernel(const int* __restrict__ dst, int* __restrict__ cnt, int E) {
  int i = blockIdx.x * blockDim.x + threadIdx.x;
  if (i < E) atomicAdd(&cnt[dst[i]], 1);
}

static constexpr int kScanChunk = 2048;  // 256 threads x 8 elems

__global__ void scan1_kernel(const int* __restrict__ in, int* __restrict__ out,
                             int* __restrict__ bsums, int N) {
  __shared__ int sm[256];
  int base = blockIdx.x * kScanChunk + threadIdx.x * 8;
  int v[8];
  int ls = 0;
  #pragma unroll
  for (int j = 0; j < 8; ++j) {
    int idx = base + j;
    int x = (idx < N) ? in[idx] : 0;
    v[j] = x; ls += x;
  }
  sm[threadIdx.x] = ls;
  __syncthreads();
  // Hillis-Steele inclusive scan over thread sums
  for (int off = 1; off < 256; off <<= 1) {
    int t = (threadIdx.x >= off) ? sm[threadIdx.x - off] : 0;
    __syncthreads();
    sm[threadIdx.x] += t;
    __syncthreads();
  }
  int excl = sm[threadIdx.x] - ls;
  if (threadIdx.x == 255) bsums[blockIdx.x] = sm[255];
  int run = excl;
  #pragma unroll
  for (int j = 0; j < 8; ++j) {
    int idx = base + j;
    if (idx < N) out[idx] = run;
    run += v[j];
  }
}

__global__ void scan2_kernel(int* __restrict__ bsums, int nb) {
  if (blockIdx.x == 0 && threadIdx.x == 0) {
    int run = 0;
    for (int i = 0; i < nb; ++i) { int t = bsums[i]; bsums[i] = run; run += t; }
  }
}

__global__ void scan3_kernel(int* __restrict__ out, const int* __restrict__ bsums,
                             int N, int total) {
  int add = bsums[blockIdx.x];
  int base = blockIdx.x * kScanChunk + threadIdx.x * 8;
  #pragma unroll
  for (int j = 0; j < 8; ++j) {
    int idx = base + j;
    if (idx < N) out[idx] += add;
  }
  if (blockIdx.x == 0 && threadIdx.x == 0) out[N] = total;
}

__global__ void scatter_kernel(const int* __restrict__ src, const int* __restrict__ dst,
                               const int* __restrict__ offs, int* __restrict__ cur,
                               int* __restrict__ csrc, int E) {
  int i = blockIdx.x * blockDim.x + threadIdx.x;
  if (i < E) {
    int d = dst[i];
    int pos = atomicAdd(&cur[d], 1);
    csrc[offs[d] + pos] = src[i];
  }
}

// ---------------------------------------------------------------------------
// GAT aggregate: one wave per dst node. lane = output dim (h = lane>>5, c = lane&31).
// Pass 1: online softmax stats per half-wave. Pass 2: alpha-weighted gather of hs[src].
// ---------------------------------------------------------------------------
__global__ void gat_agg_kernel(const int* __restrict__ offs, const int* __restrict__ csrc,
                               const float* __restrict__ HS, const float* __restrict__ ALS,
                               const float* __restrict__ ALD, const float* __restrict__ bias,
                               float* __restrict__ out, int Nd) {
  int wave = threadIdx.x >> 6;
  int lane = threadIdx.x & 63;
  int dst = blockIdx.x * (blockDim.x >> 6) + wave;
  if (dst >= Nd) return;
  int h = lane >> 5, c = lane & 31;
  int beg = offs[dst], end = offs[dst + 1];
  float bval = bias[lane];
  if (beg == end) {  // no incoming edges: segment sums are 0
    out[(size_t)dst * kHO + lane] = bval;
    return;
  }
  float aldh = ALD[(size_t)dst * 2 + h];
  // online (max, sumexp) over edges, strided across the 32 lanes of this head
  float m = -INFINITY, s = 0.f;
  for (int i = beg + c; i < end; i += 32) {
    int sv = csrc[i];
    float logit = ALS[(size_t)sv * 2 + h] + aldh;
    logit = logit > 0.f ? logit : 0.2f * logit;
    if (logit > m) { s = s * __expf(m - logit) + 1.f; m = logit; }
    else            s += __expf(logit - m);
  }
  // combine the 32 lanes of each half-wave
  for (int off = 16; off >= 1; off >>= 1) {
    float mo = __shfl_xor(m, off);
    float so = __shfl_xor(s, off);
    float mn = fmaxf(m, mo);
    float sa = (m  == -INFINITY) ? 0.f : s  * __expf(m  - mn);
    float sb = (mo == -INFINITY) ? 0.f : so * __expf(mo - mn);
    m = mn; s = sa + sb;
  }
  float inv_denom = 1.f / (s + 1e-16f);
  // pass 2: alpha-weighted accumulation of hs[src] (coalesced 256B per edge)
  float acc = 0.f;
  for (int i = beg; i < end; ++i) {
    int sv = csrc[i];  // uniform across wave -> broadcast load
    float logit = ALS[(size_t)sv * 2 + h] + aldh;  // uniform across half-wave
    logit = logit > 0.f ? logit : 0.2f * logit;
    float alpha = __expf(logit - m) * inv_denom;
    acc = fmaf(alpha, HS[(size_t)sv * kHO + lane], acc);
  }
  out[(size_t)dst * kHO + lane] = acc + bval;
}

// ---------------------------------------------------------------------------
// LayerNorm (+optional residual) + ELU, one wave per row of 64.
// ---------------------------------------------------------------------------
__global__ void ln_kernel(const float* __restrict__ X, const float* __restrict__ g,
                          const float* __restrict__ be, const float* __restrict__ res,
                          float* __restrict__ out, int N, int use_res) {
  int row = blockIdx.x * (blockDim.x >> 6) + (threadIdx.x >> 6);
  int lane = threadIdx.x & 63;
  if (row >= N) return;
  float x = X[(size_t)row * kHO + lane];
  float sum = x, sq = x * x;
  for (int off = 32; off >= 1; off >>= 1) {
    sum += __shfl_xor(sum, off);
    sq  += __shfl_xor(sq, off);
  }
  float mu = sum * (1.f / kHO);
  float var = sq * (1.f / kHO) - mu * mu;
  float y = (x - mu) * rsqrtf(var + 1e-5f) * g[lane] + be[lane];
  if (use_res) y += res[(size_t)row * kHO + lane];
  out[(size_t)row * kHO + lane] = y > 0.f ? y : expm1f(y);
}

// ---------------------------------------------------------------------------
// Final projection: out[N,64] = X[N,64] @ Wo[64,64] + bo
// ---------------------------------------------------------------------------
__global__ void outproj_kernel(const float* __restrict__ X, const float* __restrict__ W,
                               const float* __restrict__ bias, float* __restrict__ out, int N) {
  __shared__ float Wl[kHO * kHO];
  for (int i = threadIdx.x; i < kHO * kHO; i += blockDim.x) Wl[i] = W[i];
  __syncthreads();
  int row = blockIdx.x * (blockDim.x >> 6) + (threadIdx.x >> 6);
  int col = threadIdx.x & 63;
  if (row >= N) return;
  const float* xr = X + (size_t)row * kHO;
  float acc = 0.f;
  #pragma unroll
  for (int k = 0; k < kHO; ++k) acc = fmaf(xr[k], Wl[k * kHO + col], acc);
  out[(size_t)row * kHO + col] = acc + bias[col];
}

// ---------------------------------------------------------------------------
// Host launcher
// ---------------------------------------------------------------------------
extern "C" void kernel_launch(void* const* d_in, const int* in_sizes, int n_in,
                              void* d_out, int out_size, void* d_ws, size_t ws_size,
                              hipStream_t stream) {
  const float* x_tx    = (const float*)d_in[0];
  const float* x_addr  = (const float*)d_in[1];
  const float* Wp_tx   = (const float*)d_in[2];
  const float* bp_tx   = (const float*)d_in[3];
  const float* Wp_addr = (const float*)d_in[4];
  const float* bp_addr = (const float*)d_in[5];
  const float* W_ta0   = (const float*)d_in[6];
  const float* as_ta0  = (const float*)d_in[7];
  const float* ad_ta0  = (const float*)d_in[8];
  const float* b_ta0   = (const float*)d_in[9];
  const float* W_at0   = (const float*)d_in[10];
  const float* as_at0  = (const float*)d_in[11];
  const float* ad_at0  = (const float*)d_in[12];
  const float* b_at0   = (const float*)d_in[13];
  const float* W_ta1   = (const float*)d_in[14];
  const float* as_ta1  = (const float*)d_in[15];
  const float* ad_ta1  = (const float*)d_in[16];
  const float* b_ta1   = (const float*)d_in[17];
  const float* W_at1   = (const float*)d_in[18];
  const float* as_at1  = (const float*)d_in[19];
  const float* ad_at1  = (const float*)d_in[20];
  const float* b_at1   = (const float*)d_in[21];
  const float* g_tx    = (const float*)d_in[22];
  const float* be_tx   = (const float*)d_in[23];
  const float* g_addr  = (const float*)d_in[24];
  const float* be_addr = (const float*)d_in[25];
  const float* Wo      = (const float*)d_in[26];
  const float* bo      = (const float*)d_in[27];
  const int* e_src_ta  = (const int*)d_in[28];
  const int* e_dst_ta  = (const int*)d_in[29];
  const int* e_src_at  = (const int*)d_in[30];
  const int* e_dst_at  = (const int*)d_in[31];
  (void)in_sizes; (void)n_in; (void)out_size; (void)ws_size;

  // Workspace carve-up (~216 MB total)
  char* p = (char*)d_ws;
  auto alloc = [&](size_t bytes) { char* r = p; p += (bytes + 255) & ~(size_t)255; return r; };
  float* txp  = (float*)alloc((size_t)kNTx   * kHid * 4);  // layer-0 tx features [N_TX,32]
  float* adp  = (float*)alloc((size_t)kNAddr * kHid * 4);  // layer-0 addr features [N_ADDR,32]
  float* txf  = (float*)alloc((size_t)kNTx   * kHO * 4);   // current tx features [N_TX,64]
  float* adf  = (float*)alloc((size_t)kNAddr * kHO * 4);   // current addr features [N_ADDR,64]
  float* hs   = (float*)alloc((size_t)kNAddr * kHO * 4);   // per-relation source hs (reused)
  float* aggA = (float*)alloc((size_t)kNAddr * kHO * 4);   // new_ad
  float* aggT = (float*)alloc((size_t)kNTx   * kHO * 4);   // new_tx
  float* als  = (float*)alloc((size_t)kNAddr * 2 * 4);
  float* ald  = (float*)alloc((size_t)kNAddr * 2 * 4);
  int* offs_ta = (int*)alloc((size_t)(kNAddr + 1) * 4);
  int* cur_ta  = (int*)alloc((size_t)kNAddr * 4);
  int* srcs_ta = (int*)alloc((size_t)kE * 4);
  int* offs_at = (int*)alloc((size_t)(kNTx + 1) * 4);
  int* cur_at  = (int*)alloc((size_t)kNTx * 4);
  int* srcs_at = (int*)alloc((size_t)kE * 4);
  int* bsums   = (int*)alloc(1024 * 4);

  const int EB = (kE + 255) / 256;

  // ---- CSR build (once; reused by both layers) ----
  auto build_csr = [&](const int* esrc, const int* edst, int Nd,
                       int* offs, int* cur, int* csrc) {
    hipMemsetAsync(cur, 0, (size_t)Nd * 4, stream);
    count_kernel<<<EB, 256, 0, stream>>>(edst, cur, kE);
    int nb = (Nd + kScanChunk - 1) / kScanChunk;
    scan1_kernel<<<nb, 256, 0, stream>>>(cur, offs, bsums, Nd);
    scan2_kernel<<<1, 64, 0, stream>>>(bsums, nb);
    scan3_kernel<<<nb, 256, 0, stream>>>(offs, bsums, Nd, kE);
    hipMemsetAsync(cur, 0, (size_t)Nd * 4, stream);
    scatter_kernel<<<EB, 256, 0, stream>>>(esrc, edst, offs, cur, csrc, kE);
  };
  build_csr(e_src_ta, e_dst_ta, kNAddr, offs_ta, cur_ta, srcs_ta);
  build_csr(e_src_at, e_dst_at, kNTx,   offs_at, cur_at, srcs_at);

  // ---- Input projections ----
  proj_kernel<kFTx><<<(kNTx + 7) / 8, 256, 0, stream>>>(x_tx, Wp_tx, bp_tx, txp, kNTx);
  proj_kernel<kFAddr><<<(kNAddr + 7) / 8, 256, 0, stream>>>(x_addr, Wp_addr, bp_addr, adp, kNAddr);

  // ---- Layer 0 (K=32, no residual) ----
  // relation tx->addr
  hs_als_kernel<kHid><<<(kNTx + 3) / 4, 256, 0, stream>>>(txp, W_ta0, as_ta0, hs, als, kNTx);
  ald_kernel<kHid><<<(kNAddr + 127) / 128, 256, 0, stream>>>(adp, W_ta0, ad_ta0, ald, kNAddr);
  gat_agg_kernel<<<(kNAddr + 3) / 4, 256, 0, stream>>>(offs_ta, srcs_ta, hs, als, ald, b_ta0, aggA, kNAddr);
  // relation addr->tx
  hs_als_kernel<kHid><<<(kNAddr + 3) / 4, 256, 0, stream>>>(adp, W_at0, as_at0, hs, als, kNAddr);
  ald_kernel<kHid><<<(kNTx + 127) / 128, 256, 0, stream>>>(txp, W_at0, ad_at0, ald, kNTx);
  gat_agg_kernel<<<(kNTx + 3) / 4, 256, 0, stream>>>(offs_at, srcs_at, hs, als, ald, b_at0, aggT, kNTx);
  // LN + ELU (no residual: shapes 32 vs 64 differ)
  ln_kernel<<<(kNTx + 3) / 4, 256, 0, stream>>>(aggT, g_tx, be_tx, txf, txf, kNTx, 0);
  ln_kernel<<<(kNAddr + 3) / 4, 256, 0, stream>>>(aggA, g_addr, be_addr, adf, adf, kNAddr, 0);

  // ---- Layer 1 (K=64, residual) ----
  hs_als_kernel<kHO><<<(kNTx + 3) / 4, 256, 0, stream>>>(txf, W_ta1, as_ta1, hs, als, kNTx);
  ald_kernel<kHO><<<(kNAddr + 127) / 128, 256, 0, stream>>>(adf, W_ta1, ad_ta1, ald, kNAddr);
  gat_agg_kernel<<<(kNAddr + 3) / 4, 256, 0, stream>>>(offs_ta, srcs_ta, hs, als, ald, b_ta1, aggA, kNAddr);
  hs_als_kernel<kHO><<<(kNAddr + 3) / 4, 256, 0, stream>>>(adf, W_at1, as_at1, hs, als, kNAddr);
  ald_kernel<kHO><<<(kNTx + 127) / 128, 256, 0, stream>>>(txf, W_at1, ad_at1, ald, kNTx);
  gat_agg_kernel<<<(kNTx + 3) / 4, 256, 0, stream>>>(offs_at, srcs_at, hs, als, ald, b_at1, aggT, kNTx);
  ln_kernel<<<(kNTx + 3) / 4, 256, 0, stream>>>(aggT, g_tx, be_tx, txf, txf, kNTx, 1);
  ln_kernel<<<(kNAddr + 3) / 4, 256, 0, stream>>>(aggA, g_addr, be_addr, adf, adf, kNAddr, 1);

  // ---- Output projection ----
  outproj_kernel<<<(kNTx + 3) / 4, 256, 0, stream>>>(txf, Wo, bo, (float*)d_out, kNTx);
}